// Round 1
// baseline (165.181 us; speedup 1.0000x reference)
//
#include <hip/hip_runtime.h>
#include <math.h>

// Problem: B=16384, D=512, R=64, E=8.
// out = x0 * (sum_e g_e * (x @ V[e]^T C[e] U[e]^T)) + g@b + x*sum(g)
// Folded: VC[d, e*R+s] = sum_r V[e,r,d] C[e,r,s]  ->  xvc = x @ VC   (GEMM1)
//         t = g-scaled xvc (expert = col/64)      ->  gproj = t @ Ustack (GEMM2)

typedef __bf16 bf16_t;
typedef __attribute__((ext_vector_type(8))) __bf16 bf16x8;
typedef __attribute__((ext_vector_type(4))) __bf16 bf16x4;
typedef __attribute__((ext_vector_type(4))) float  floatx4;

// ---------------- async 16B/lane global->LDS (LDS dest = wave-uniform base + lane*16)
__device__ __forceinline__ void async16(void* lds, const void* gp) {
  __builtin_amdgcn_global_load_lds(
      (__attribute__((address_space(1))) void*)(gp),
      (__attribute__((address_space(3))) void*)(lds), 16, 0, 0);
}

// ---------------- K0: weight prep ------------------------------------------
// VCc[n][d] (n=e*64+s): Bt layout for GEMM1 B-operand, bf16 [512][512]
// Ut [d][j] (j=e*64+s): Bt layout for GEMM2 B-operand, bf16 [512][512]
__global__ __launch_bounds__(256) void prep_kernel(
    const float* __restrict__ U, const float* __restrict__ V, const float* __restrict__ C,
    bf16_t* __restrict__ VCc, bf16_t* __restrict__ Ut) {
  int tid = blockIdx.x * 256 + threadIdx.x;
  if (tid < 512 * 512) {
    int n = tid >> 9, d = tid & 511;
    int e = n >> 6, s = n & 63;
    const float* Vp = V + (size_t)e * 64 * 512 + d;   // V[e,r,d], stride 512 over r
    const float* Cp = C + (size_t)e * 64 * 64 + s;    // C[e,r,s], stride 64 over r
    float acc = 0.f;
#pragma unroll 8
    for (int r = 0; r < 64; ++r) acc += Vp[(size_t)r * 512] * Cp[r * 64];
    VCc[tid] = (bf16_t)acc;
  } else {
    int i2 = tid - 512 * 512;
    int d = i2 >> 9, n = i2 & 511;
    int e = n >> 6, s = n & 63;
    Ut[i2] = (bf16_t)U[((size_t)e * 512 + d) * 64 + s];
  }
}

// ---------------- K1: x -> bf16 cast + gate softmax (one wave per row) -----
__global__ __launch_bounds__(256) void gate_kernel(
    const float* __restrict__ x, const float* __restrict__ Wg, const float* __restrict__ bg,
    bf16_t* __restrict__ xbf, float* __restrict__ g) {
  int wave = threadIdx.x >> 6, lane = threadIdx.x & 63;
  int row = blockIdx.x * 4 + wave;
  const float4* xr = (const float4*)(x + (size_t)row * 512);
  float4 v0 = xr[lane];
  float4 v1 = xr[lane + 64];
  bf16x4* xb = (bf16x4*)(xbf + (size_t)row * 512);
  bf16x4 b0, b1;
  b0.x = (bf16_t)v0.x; b0.y = (bf16_t)v0.y; b0.z = (bf16_t)v0.z; b0.w = (bf16_t)v0.w;
  b1.x = (bf16_t)v1.x; b1.y = (bf16_t)v1.y; b1.z = (bf16_t)v1.z; b1.w = (bf16_t)v1.w;
  xb[lane] = b0;
  xb[lane + 64] = b1;
  float acc[8];
#pragma unroll
  for (int e = 0; e < 8; ++e) {
    const float4* wp = (const float4*)(Wg + (size_t)e * 512);
    float4 w0 = wp[lane], w1 = wp[lane + 64];
    acc[e] = v0.x * w0.x + v0.y * w0.y + v0.z * w0.z + v0.w * w0.w +
             v1.x * w1.x + v1.y * w1.y + v1.z * w1.z + v1.w * w1.w;
  }
#pragma unroll
  for (int e = 0; e < 8; ++e) {
#pragma unroll
    for (int off = 32; off > 0; off >>= 1) acc[e] += __shfl_xor(acc[e], off, 64);
  }
  float z[8], mx = -1e30f;
#pragma unroll
  for (int e = 0; e < 8; ++e) { z[e] = acc[e] + bg[e]; mx = fmaxf(mx, z[e]); }
  float s = 0.f;
#pragma unroll
  for (int e = 0; e < 8; ++e) { z[e] = __expf(z[e] - mx); s += z[e]; }
  float inv = 1.f / s;
  if (lane == 0) {
#pragma unroll
    for (int e = 0; e < 8; ++e) g[(size_t)row * 8 + e] = z[e] * inv;
  }
}

// ---------------- shared GEMM core: 128x128 tile, BK=64, 4 waves 2x2 -------
// A [M][512] bf16 row-major; Bt [N][512] bf16 (column n's K contiguous).
// LDS chunk swizzle: 16B chunk q of row r holds global chunk q^(r&7)
// -> fragment ds_read_b128 spreads across all 32 banks (2-way = free).
__device__ __forceinline__ void gemm_core(
    const bf16_t* __restrict__ A, const bf16_t* __restrict__ Bt,
    int m0, int n0, int t, floatx4 acc[4][4]) {
  __shared__ char lds[32768];
  char* ldsA = lds;           // [128 rows][128B]
  char* ldsB = lds + 16384;   // [128 cols][128B]
  const int wave = t >> 6, lane = t & 63;
  const int wr = wave >> 1, wc = wave & 1;
  const int lhi = lane >> 4, llo = lane & 15;
#pragma unroll 1
  for (int it = 0; it < 8; ++it) {
    const int k0 = it * 64;
    __syncthreads();  // protect LDS from previous iter's readers
#pragma unroll
    for (int i = 0; i < 4; ++i) {
      int c = i * 256 + t;                 // this thread's LDS 16B slot index
      int r = c >> 3, q = c & 7;
      int p = q ^ (r & 7);                 // fetch swizzled source chunk
      const char* ga = (const char*)A + (size_t)(m0 + r) * 1024 + k0 * 2 + p * 16;
      async16(ldsA + (i * 256 + wave * 64) * 16, ga);
      const char* gb = (const char*)Bt + (size_t)(n0 + r) * 1024 + k0 * 2 + p * 16;
      async16(ldsB + (i * 256 + wave * 64) * 16, gb);
    }
    __syncthreads();  // drains vmcnt (global_load_lds) per barrier semantics
#pragma unroll
    for (int ks = 0; ks < 2; ++ks) {
      bf16x8 af[4], bfm[4];
#pragma unroll
      for (int i = 0; i < 4; ++i) {
        int rA = wr * 64 + i * 16 + llo;   // A-frag: row=lane&15(+tile), k=quad*8+j
        af[i]  = *(const bf16x8*)(ldsA + rA * 128 + (((ks * 4 + lhi) ^ (rA & 7)) << 4));
        int rB = wc * 64 + i * 16 + llo;   // B-frag: col=lane&15(+tile), k=quad*8+j
        bfm[i] = *(const bf16x8*)(ldsB + rB * 128 + (((ks * 4 + lhi) ^ (rB & 7)) << 4));
      }
#pragma unroll
      for (int i = 0; i < 4; ++i)
#pragma unroll
        for (int j = 0; j < 4; ++j)
          acc[i][j] = __builtin_amdgcn_mfma_f32_16x16x32_bf16(af[i], bfm[j], acc[i][j], 0, 0, 0);
    }
  }
}

// ---------------- K2: GEMM1 + gate-scale epilogue -> t (bf16) --------------
__global__ __launch_bounds__(256, 2) void gemm1_kernel(
    const bf16_t* __restrict__ xbf, const bf16_t* __restrict__ VCc,
    const float* __restrict__ g, bf16_t* __restrict__ T) {
  int t = threadIdx.x;
  int m0 = blockIdx.x * 128, n0 = blockIdx.y * 128;
  floatx4 acc[4][4];
#pragma unroll
  for (int i = 0; i < 4; ++i)
#pragma unroll
    for (int j = 0; j < 4; ++j) acc[i][j] = (floatx4){0.f, 0.f, 0.f, 0.f};
  gemm_core(xbf, VCc, m0, n0, t, acc);
  const int wave = t >> 6, lane = t & 63;
  const int wr = wave >> 1, wc = wave & 1;
  const int lhi = lane >> 4, llo = lane & 15;
  const int e = (n0 + wc * 64) >> 6;  // wave's 64-col slab = one expert (R=64 aligned)
#pragma unroll
  for (int i = 0; i < 4; ++i) {
#pragma unroll
    for (int r = 0; r < 4; ++r) {
      int m = m0 + wr * 64 + i * 16 + lhi * 4 + r;  // C/D: col=lane&15, row=quad*4+reg
      float gv = g[(size_t)m * 8 + e];
#pragma unroll
      for (int j = 0; j < 4; ++j) {
        int n = n0 + wc * 64 + j * 16 + llo;
        T[(size_t)m * 512 + n] = (bf16_t)(acc[i][j][r] * gv);
      }
    }
  }
}

// ---------------- K3: GEMM2 + final epilogue -> out (f32) ------------------
__global__ __launch_bounds__(256, 2) void gemm2_kernel(
    const bf16_t* __restrict__ T, const bf16_t* __restrict__ Ut,
    const float* __restrict__ g, const float* __restrict__ bvec,
    const float* __restrict__ x0, const float* __restrict__ x,
    float* __restrict__ out) {
  int t = threadIdx.x;
  int m0 = blockIdx.x * 128, n0 = blockIdx.y * 128;
  floatx4 acc[4][4];
#pragma unroll
  for (int i = 0; i < 4; ++i)
#pragma unroll
    for (int j = 0; j < 4; ++j) acc[i][j] = (floatx4){0.f, 0.f, 0.f, 0.f};
  gemm_core(T, Ut, m0, n0, t, acc);
  const int wave = t >> 6, lane = t & 63;
  const int wr = wave >> 1, wc = wave & 1;
  const int lhi = lane >> 4, llo = lane & 15;
  float bb4[4][8];  // bvec[e][n_j] for this lane's 4 column positions
#pragma unroll
  for (int j = 0; j < 4; ++j) {
    int n = n0 + wc * 64 + j * 16 + llo;
#pragma unroll
    for (int e = 0; e < 8; ++e) bb4[j][e] = bvec[(size_t)e * 512 + n];
  }
#pragma unroll
  for (int i = 0; i < 4; ++i) {
#pragma unroll
    for (int r = 0; r < 4; ++r) {
      int m = m0 + wr * 64 + i * 16 + lhi * 4 + r;
      float g8[8], gsum = 0.f;
#pragma unroll
      for (int e = 0; e < 8; ++e) { g8[e] = g[(size_t)m * 8 + e]; gsum += g8[e]; }
#pragma unroll
      for (int j = 0; j < 4; ++j) {
        int n = n0 + wc * 64 + j * 16 + llo;
        float bias = 0.f;
#pragma unroll
        for (int e = 0; e < 8; ++e) bias += g8[e] * bb4[j][e];
        size_t idx = (size_t)m * 512 + n;
        out[idx] = x0[idx] * acc[i][j][r] + bias + x[idx] * gsum;
      }
    }
  }
}

// ---------------- launch ----------------------------------------------------
extern "C" void kernel_launch(void* const* d_in, const int* in_sizes, int n_in,
                              void* d_out, int out_size, void* d_ws, size_t ws_size,
                              hipStream_t stream) {
  const float* x0 = (const float*)d_in[0];
  const float* x  = (const float*)d_in[1];
  const float* U  = (const float*)d_in[2];
  const float* V  = (const float*)d_in[3];
  const float* C  = (const float*)d_in[4];
  const float* bv = (const float*)d_in[5];
  const float* Wg = (const float*)d_in[6];
  const float* bg = (const float*)d_in[7];
  float* out = (float*)d_out;

  char* ws = (char*)d_ws;
  bf16_t* xbf = (bf16_t*)(ws);                               // 16,777,216 B
  bf16_t* T   = (bf16_t*)(ws + 16777216);                    // 16,777,216 B
  bf16_t* VCc = (bf16_t*)(ws + 33554432);                    //    524,288 B
  bf16_t* Ut  = (bf16_t*)(ws + 34078720);                    //    524,288 B
  float*  g   = (float*)(ws + 34603008);                     //    524,288 B

  prep_kernel<<<2048, 256, 0, stream>>>(U, V, C, VCc, Ut);
  gate_kernel<<<4096, 256, 0, stream>>>(x, Wg, bg, xbf, g);
  gemm1_kernel<<<dim3(128, 4), 256, 0, stream>>>(xbf, VCc, g, T);
  gemm2_kernel<<<dim3(128, 4), 256, 0, stream>>>(T, Ut, g, bv, x0, x, out);
}

// Round 2
// 163.225 us; speedup vs baseline: 1.0120x; 1.0120x over previous
//
#include <hip/hip_runtime.h>
#include <math.h>

// Problem: B=16384, D=512, R=64, E=8.
// out = x0 * (sum_e g_e * (x @ V[e]^T C[e] U[e]^T)) + g@b + x*sum(g)
// Folded: VC[d, e*R+s] = sum_r V[e,r,d] C[e,r,s]  ->  xvc = x @ VC   (GEMM1)
//         t = g-scaled xvc (expert = col/64)      ->  gproj = t @ Ustack (GEMM2)
// R2: 128x64 tiles -> grid (128,8)=1024 blocks, 4 blocks/CU, 16 waves/CU.
//     grid.x = m-block so XCD = m%8 -> the 8 n-blocks of one m-slab share an XCD (A L2-local).

typedef __bf16 bf16_t;
typedef __attribute__((ext_vector_type(8))) __bf16 bf16x8;
typedef __attribute__((ext_vector_type(4))) __bf16 bf16x4;
typedef __attribute__((ext_vector_type(4))) float  floatx4;

// async 16B/lane global->LDS (LDS dest = wave-uniform base + lane*16)
__device__ __forceinline__ void async16(void* lds, const void* gp) {
  __builtin_amdgcn_global_load_lds(
      (__attribute__((address_space(1))) void*)(gp),
      (__attribute__((address_space(3))) void*)(lds), 16, 0, 0);
}

// ---------------- K0: weight prep ------------------------------------------
// VCc[n][d] (n=e*64+s): Bt layout for GEMM1 B-operand, bf16 [512][512]
// Ut [d][j] (j=e*64+s): Bt layout for GEMM2 B-operand, bf16 [512][512]
__global__ __launch_bounds__(256) void prep_kernel(
    const float* __restrict__ U, const float* __restrict__ V, const float* __restrict__ C,
    bf16_t* __restrict__ VCc, bf16_t* __restrict__ Ut) {
  int tid = blockIdx.x * 256 + threadIdx.x;
  if (tid < 512 * 512) {
    int n = tid >> 9, d = tid & 511;
    int e = n >> 6, s = n & 63;
    const float* Vp = V + (size_t)e * 64 * 512 + d;   // V[e,r,d], stride 512 over r
    const float* Cp = C + (size_t)e * 64 * 64 + s;    // C[e,r,s], stride 64 over r (wave-uniform)
    float acc = 0.f;
#pragma unroll 8
    for (int r = 0; r < 64; ++r) acc += Vp[(size_t)r * 512] * Cp[r * 64];
    VCc[tid] = (bf16_t)acc;
  } else {
    int i2 = tid - 512 * 512;
    int d = i2 >> 9, n = i2 & 511;
    int e = n >> 6, s = n & 63;
    Ut[i2] = (bf16_t)U[((size_t)e * 512 + d) * 64 + s];
  }
}

// ---------------- K1: x -> bf16 cast + gate softmax (one wave per row) -----
__global__ __launch_bounds__(256) void gate_kernel(
    const float* __restrict__ x, const float* __restrict__ Wg, const float* __restrict__ bg,
    bf16_t* __restrict__ xbf, float* __restrict__ g) {
  int wave = threadIdx.x >> 6, lane = threadIdx.x & 63;
  int row = blockIdx.x * 4 + wave;
  const float4* xr = (const float4*)(x + (size_t)row * 512);
  float4 v0 = xr[lane];
  float4 v1 = xr[lane + 64];
  bf16x4* xb = (bf16x4*)(xbf + (size_t)row * 512);
  bf16x4 b0, b1;
  b0.x = (bf16_t)v0.x; b0.y = (bf16_t)v0.y; b0.z = (bf16_t)v0.z; b0.w = (bf16_t)v0.w;
  b1.x = (bf16_t)v1.x; b1.y = (bf16_t)v1.y; b1.z = (bf16_t)v1.z; b1.w = (bf16_t)v1.w;
  xb[lane] = b0;
  xb[lane + 64] = b1;
  float acc[8];
#pragma unroll
  for (int e = 0; e < 8; ++e) {
    const float4* wp = (const float4*)(Wg + (size_t)e * 512);
    float4 w0 = wp[lane], w1 = wp[lane + 64];
    acc[e] = v0.x * w0.x + v0.y * w0.y + v0.z * w0.z + v0.w * w0.w +
             v1.x * w1.x + v1.y * w1.y + v1.z * w1.z + v1.w * w1.w;
  }
#pragma unroll
  for (int e = 0; e < 8; ++e) {
#pragma unroll
    for (int off = 32; off > 0; off >>= 1) acc[e] += __shfl_xor(acc[e], off, 64);
  }
  float z[8], mx = -1e30f;
#pragma unroll
  for (int e = 0; e < 8; ++e) { z[e] = acc[e] + bg[e]; mx = fmaxf(mx, z[e]); }
  float s = 0.f;
#pragma unroll
  for (int e = 0; e < 8; ++e) { z[e] = __expf(z[e] - mx); s += z[e]; }
  float inv = 1.f / s;
  if (lane == 0) {
#pragma unroll
    for (int e = 0; e < 8; ++e) g[(size_t)row * 8 + e] = z[e] * inv;
  }
}

// ---------------- shared GEMM core: 128x64 tile, BK=64, 4 waves 2x2 --------
// A [M][512] bf16 row-major; Bt [N][512] bf16 (column n's K contiguous).
// LDS chunk swizzle: 16B chunk slot q of row r holds global chunk q^(r&7)
// -> fragment ds_read_b128 spreads across banks (2-way = free, m136).
// Wave-tile 64(m) x 32(n): acc[4][2].
__device__ __forceinline__ void gemm_core64(
    const bf16_t* __restrict__ A, const bf16_t* __restrict__ Bt,
    int m0, int n0, int t, floatx4 acc[4][2]) {
  __shared__ char lds[24576];
  char* ldsA = lds;           // [128 rows][128B]
  char* ldsB = lds + 16384;   // [ 64 cols][128B]
  const int wave = t >> 6, lane = t & 63;
  const int wr = wave >> 1, wc = wave & 1;
  const int lhi = lane >> 4, llo = lane & 15;
#pragma unroll 1
  for (int it = 0; it < 8; ++it) {
    const int k0 = it * 64;
    __syncthreads();  // protect LDS from previous iter's readers
#pragma unroll
    for (int i = 0; i < 4; ++i) {          // A: 1024 slots of 16B
      int c = i * 256 + t;
      int r = c >> 3, q = c & 7;
      int p = q ^ (r & 7);
      async16(ldsA + (i * 256 + wave * 64) * 16,
              (const char*)A + (size_t)(m0 + r) * 1024 + k0 * 2 + p * 16);
    }
#pragma unroll
    for (int i = 0; i < 2; ++i) {          // B: 512 slots of 16B
      int c = i * 256 + t;
      int r = c >> 3, q = c & 7;
      int p = q ^ (r & 7);
      async16(ldsB + (i * 256 + wave * 64) * 16,
              (const char*)Bt + (size_t)(n0 + r) * 1024 + k0 * 2 + p * 16);
    }
    __syncthreads();  // drains vmcnt per barrier semantics
#pragma unroll
    for (int ks = 0; ks < 2; ++ks) {
      bf16x8 af[4], bfm[2];
#pragma unroll
      for (int i = 0; i < 4; ++i) {
        int rA = wr * 64 + i * 16 + llo;   // A-frag: row=lane&15(+tile), k=quad*8+j
        af[i] = *(const bf16x8*)(ldsA + rA * 128 + (((ks * 4 + lhi) ^ (rA & 7)) << 4));
      }
#pragma unroll
      for (int j = 0; j < 2; ++j) {
        int rB = wc * 32 + j * 16 + llo;   // B-frag: col=lane&15(+tile), k=quad*8+j
        bfm[j] = *(const bf16x8*)(ldsB + rB * 128 + (((ks * 4 + lhi) ^ (rB & 7)) << 4));
      }
#pragma unroll
      for (int i = 0; i < 4; ++i)
#pragma unroll
        for (int j = 0; j < 2; ++j)
          acc[i][j] = __builtin_amdgcn_mfma_f32_16x16x32_bf16(af[i], bfm[j], acc[i][j], 0, 0, 0);
    }
  }
}

// ---------------- K2: GEMM1 + gate-scale epilogue -> t (bf16) --------------
__global__ __launch_bounds__(256, 4) void gemm1_kernel(
    const bf16_t* __restrict__ xbf, const bf16_t* __restrict__ VCc,
    const float* __restrict__ g, bf16_t* __restrict__ T) {
  int t = threadIdx.x;
  int m0 = blockIdx.x * 128, n0 = blockIdx.y * 64;
  floatx4 acc[4][2];
#pragma unroll
  for (int i = 0; i < 4; ++i)
#pragma unroll
    for (int j = 0; j < 2; ++j) acc[i][j] = (floatx4){0.f, 0.f, 0.f, 0.f};
  gemm_core64(xbf, VCc, m0, n0, t, acc);
  const int wave = t >> 6, lane = t & 63;
  const int wr = wave >> 1, wc = wave & 1;
  const int lhi = lane >> 4, llo = lane & 15;
  const int e = n0 >> 6;  // 64-wide n-block = one expert (wave-uniform)
#pragma unroll
  for (int i = 0; i < 4; ++i) {
#pragma unroll
    for (int r = 0; r < 4; ++r) {
      int m = m0 + wr * 64 + i * 16 + lhi * 4 + r;  // C/D: col=lane&15, row=quad*4+reg
      float gv = g[(size_t)m * 8 + e];
#pragma unroll
      for (int j = 0; j < 2; ++j) {
        int n = n0 + wc * 32 + j * 16 + llo;
        T[(size_t)m * 512 + n] = (bf16_t)(acc[i][j][r] * gv);
      }
    }
  }
}

// ---------------- K3: GEMM2 + final epilogue -> out (f32) ------------------
__global__ __launch_bounds__(256, 4) void gemm2_kernel(
    const bf16_t* __restrict__ T, const bf16_t* __restrict__ Ut,
    const float* __restrict__ g, const float* __restrict__ bvec,
    const float* __restrict__ x0, const float* __restrict__ x,
    float* __restrict__ out) {
  int t = threadIdx.x;
  int m0 = blockIdx.x * 128, n0 = blockIdx.y * 64;
  floatx4 acc[4][2];
#pragma unroll
  for (int i = 0; i < 4; ++i)
#pragma unroll
    for (int j = 0; j < 2; ++j) acc[i][j] = (floatx4){0.f, 0.f, 0.f, 0.f};
  gemm_core64(T, Ut, m0, n0, t, acc);
  const int wave = t >> 6, lane = t & 63;
  const int wr = wave >> 1, wc = wave & 1;
  const int lhi = lane >> 4, llo = lane & 15;
  float bb[2][8];  // bvec[e][n_j] for this lane's 2 column positions
#pragma unroll
  for (int j = 0; j < 2; ++j) {
    int n = n0 + wc * 32 + j * 16 + llo;
#pragma unroll
    for (int e = 0; e < 8; ++e) bb[j][e] = bvec[(size_t)e * 512 + n];
  }
#pragma unroll
  for (int i = 0; i < 4; ++i) {
#pragma unroll
    for (int r = 0; r < 4; ++r) {
      int m = m0 + wr * 64 + i * 16 + lhi * 4 + r;
      float g8[8], gsum = 0.f;
#pragma unroll
      for (int e = 0; e < 8; ++e) { g8[e] = g[(size_t)m * 8 + e]; gsum += g8[e]; }
#pragma unroll
      for (int j = 0; j < 2; ++j) {
        int n = n0 + wc * 32 + j * 16 + llo;
        float bias = 0.f;
#pragma unroll
        for (int e = 0; e < 8; ++e) bias += g8[e] * bb[j][e];
        size_t idx = (size_t)m * 512 + n;
        out[idx] = x0[idx] * acc[i][j][r] + bias + x[idx] * gsum;
      }
    }
  }
}

// ---------------- launch ----------------------------------------------------
extern "C" void kernel_launch(void* const* d_in, const int* in_sizes, int n_in,
                              void* d_out, int out_size, void* d_ws, size_t ws_size,
                              hipStream_t stream) {
  const float* x0 = (const float*)d_in[0];
  const float* x  = (const float*)d_in[1];
  const float* U  = (const float*)d_in[2];
  const float* V  = (const float*)d_in[3];
  const float* C  = (const float*)d_in[4];
  const float* bv = (const float*)d_in[5];
  const float* Wg = (const float*)d_in[6];
  const float* bg = (const float*)d_in[7];
  float* out = (float*)d_out;

  char* ws = (char*)d_ws;
  bf16_t* xbf = (bf16_t*)(ws);                               // 16,777,216 B
  bf16_t* T   = (bf16_t*)(ws + 16777216);                    // 16,777,216 B
  bf16_t* VCc = (bf16_t*)(ws + 33554432);                    //    524,288 B
  bf16_t* Ut  = (bf16_t*)(ws + 34078720);                    //    524,288 B
  float*  g   = (float*)(ws + 34603008);                     //    524,288 B

  prep_kernel<<<2048, 256, 0, stream>>>(U, V, C, VCc, Ut);
  gate_kernel<<<4096, 256, 0, stream>>>(x, Wg, bg, xbf, g);
  gemm1_kernel<<<dim3(128, 8), 256, 0, stream>>>(xbf, VCc, g, T);
  gemm2_kernel<<<dim3(128, 8), 256, 0, stream>>>(T, Ut, g, bv, x0, x, out);
}